// Round 6
// baseline (1694.133 us; speedup 1.0000x reference)
//
#include <hip/hip_runtime.h>
#include <hip/hip_bf16.h>
#include <hip/hip_fp16.h>

#define LRELU(v) ((v) >= 0.f ? (v) : 0.2f * (v))

typedef unsigned int uint;

static const int EPB = 2048;   // edges per bucketing block
static const int BWN = 64;     // nodes per bucket (dst >> 6)

// ---------------- feature-norm stats for x ----------------
__global__ __launch_bounds__(256) void xstats_kernel(const float4* __restrict__ x4,
                                                     float* __restrict__ xstats, int n4) {
    __shared__ float ls[32];
    if (threadIdx.x < 32) ls[threadIdx.x] = 0.f;
    __syncthreads();
    float s1[4] = {0,0,0,0}, s2[4] = {0,0,0,0};
    int stride = gridDim.x * blockDim.x;
    int j4 = (threadIdx.x & 3) * 4;  // stride % 4 == 0 -> constant per thread
    for (int i = blockIdx.x * blockDim.x + threadIdx.x; i < n4; i += stride) {
        float4 v = x4[i];
        s1[0] += v.x; s2[0] += v.x * v.x;
        s1[1] += v.y; s2[1] += v.y * v.y;
        s1[2] += v.z; s2[2] += v.z * v.z;
        s1[3] += v.w; s2[3] += v.w * v.w;
    }
    #pragma unroll
    for (int k = 0; k < 4; ++k) {
        atomicAdd(&ls[j4 + k], s1[k]);
        atomicAdd(&ls[16 + j4 + k], s2[k]);
    }
    __syncthreads();
    if (threadIdx.x < 32) atomicAdd(&xstats[threadIdx.x], ls[threadIdx.x]);
}

// normalize x and store as fp16
__global__ __launch_bounds__(256) void xnorm_kernel(const float4* __restrict__ x4,
                                                    __half2* __restrict__ xn2,
                                                    const float* __restrict__ xstats,
                                                    int n4, float invN) {
    int stride = gridDim.x * blockDim.x;
    for (int i = blockIdx.x * blockDim.x + threadIdx.x; i < n4; i += stride) {
        int j4 = (i & 3) * 4;
        float4 v = x4[i];
        float o[4], in[4] = {v.x, v.y, v.z, v.w};
        #pragma unroll
        for (int k = 0; k < 4; ++k) {
            float mu = xstats[j4 + k] * invN;
            float var = xstats[16 + j4 + k] * invN - mu * mu;
            o[k] = (in[k] - mu) * rsqrtf(var + 1e-5f);
        }
        xn2[2 * i]     = __floats2half2_rn(o[0], o[1]);
        xn2[2 * i + 1] = __floats2half2_rn(o[2], o[3]);
    }
}

// ---------------- edge-attr stats (fp32) ----------------
__global__ __launch_bounds__(256) void estats_kernel(const float4* __restrict__ e4,
                                                     float* __restrict__ estats, int E) {
    __shared__ float ls[8];
    if (threadIdx.x < 8) ls[threadIdx.x] = 0.f;
    __syncthreads();
    float s1[4] = {0,0,0,0}, s2[4] = {0,0,0,0};
    int stride = gridDim.x * blockDim.x;
    for (int e = blockIdx.x * blockDim.x + threadIdx.x; e < E; e += stride) {
        float4 v = e4[e];
        s1[0] += v.x; s2[0] += v.x * v.x;
        s1[1] += v.y; s2[1] += v.y * v.y;
        s1[2] += v.z; s2[2] += v.z * v.z;
        s1[3] += v.w; s2[3] += v.w * v.w;
    }
    #pragma unroll
    for (int k = 0; k < 4; ++k) {
        atomicAdd(&ls[k], s1[k]);
        atomicAdd(&ls[4 + k], s2[k]);
    }
    __syncthreads();
    if (threadIdx.x < 8) atomicAdd(&estats[threadIdx.x], ls[threadIdx.x]);
}

// ---------------- bucket histogram: cnt[block][bucket] (no global atomics) ----------------
__global__ __launch_bounds__(256) void histA(const int* __restrict__ ei_dst,
                                             uint* __restrict__ cnt, int E, int NB) {
    __shared__ uint hist[1024];
    int t = threadIdx.x, b = blockIdx.x;
    for (int i = t; i < NB; i += 256) hist[i] = 0;
    __syncthreads();
    int e0 = b * EPB, e1 = min(e0 + EPB, E);
    for (int e = e0 + t; e < e1; e += 256)
        atomicAdd(&hist[ei_dst[e] >> 6], 1u);
    __syncthreads();
    for (int i = t; i < NB; i += 256) cnt[(size_t)b * NB + i] = hist[i];
}

// ---------------- scan cnt columns in place: cnt[b][k] <- sum_{b'<b} cnt[b'][k]; total[k] ----------------
__global__ __launch_bounds__(256) void scanB(uint* __restrict__ cnt,
                                             uint* __restrict__ total, int NBLK, int NB) {
    int k = blockIdx.x;
    int t = threadIdx.x, lane = t & 63, w = t >> 6;
    __shared__ uint wsum[4], woff[4], ctot;
    uint carry = 0;
    int chunks = (NBLK + 255) >> 8;
    for (int c = 0; c < chunks; ++c) {
        int b = (c << 8) + t;
        uint v = (b < NBLK) ? cnt[(size_t)b * NB + k] : 0u;
        uint inc = v;
        #pragma unroll
        for (int d = 1; d < 64; d <<= 1) {
            uint u = __shfl_up(inc, d);
            if (lane >= d) inc += u;
        }
        if (lane == 63) wsum[w] = inc;
        __syncthreads();
        if (t == 0) {
            uint s = 0;
            #pragma unroll
            for (int i = 0; i < 4; ++i) { woff[i] = s; s += wsum[i]; }
            ctot = s;
        }
        __syncthreads();
        if (b < NBLK) cnt[(size_t)b * NB + k] = carry + woff[w] + inc - v;
        carry += ctot;
        __syncthreads();
    }
    if (t == 0) total[k] = carry;
}

// ---------------- exclusive scan of bucket totals -> base[NB+1] ----------------
__global__ __launch_bounds__(256) void scanB2(const uint* __restrict__ total,
                                              uint* __restrict__ base, int NB) {
    int t = threadIdx.x, lane = t & 63, w = t >> 6;
    __shared__ uint wsum[4], woff[4], ctot;
    uint carry = 0;
    int chunks = (NB + 255) >> 8;
    for (int c = 0; c < chunks; ++c) {
        int k = (c << 8) + t;
        uint v = (k < NB) ? total[k] : 0u;
        uint inc = v;
        #pragma unroll
        for (int d = 1; d < 64; d <<= 1) {
            uint u = __shfl_up(inc, d);
            if (lane >= d) inc += u;
        }
        if (lane == 63) wsum[w] = inc;
        __syncthreads();
        if (t == 0) {
            uint s = 0;
            #pragma unroll
            for (int i = 0; i < 4; ++i) { woff[i] = s; s += wsum[i]; }
            ctot = s;
        }
        __syncthreads();
        if (k < NB) base[k] = carry + woff[w] + inc - v;
        carry += ctot;
        __syncthreads();
    }
    if (t == 0) base[NB] = carry;
}

// ---------------- bucket-grouped scatter (no global atomics; disjoint ranges) ----------------
// metab[pos] = src | (dst&63)<<16 ; eab[pos] = fp16x4 of featnorm'd eattr
__global__ __launch_bounds__(256) void scatterC(const int* __restrict__ ei,
                                                const float4* __restrict__ eattr,
                                                const uint* __restrict__ cnt,
                                                const uint* __restrict__ base,
                                                const float* __restrict__ estats,
                                                uint* __restrict__ metab,
                                                uint2* __restrict__ eab,
                                                int E, int NB, float invE) {
    __shared__ uint cur[1024];
    int t = threadIdx.x, b = blockIdx.x;
    for (int i = t; i < NB; i += 256)
        cur[i] = base[i] + cnt[(size_t)b * NB + i];
    float mu[4], rs[4];
    #pragma unroll
    for (int j = 0; j < 4; ++j) {
        mu[j] = estats[j] * invE;
        float var = estats[4 + j] * invE - mu[j] * mu[j];
        rs[j] = rsqrtf(var + 1e-5f);
    }
    __syncthreads();
    int e0 = b * EPB, e1 = min(e0 + EPB, E);
    for (int e = e0 + t; e < e1; e += 256) {
        int src = ei[e];
        int dst = ei[E + e];
        float4 v = eattr[e];
        uint pos = atomicAdd(&cur[dst >> 6], 1u);
        metab[pos] = (uint)src | ((uint)(dst & 63) << 16);
        uint2 q;
        *(__half2*)&q.x = __floats2half2_rn((v.x - mu[0]) * rs[0], (v.y - mu[1]) * rs[1]);
        *(__half2*)&q.y = __floats2half2_rn((v.z - mu[2]) * rs[2], (v.w - mu[3]) * rs[3]);
        eab[pos] = q;
    }
}

// ---------------- per-bucket EA aggregation (LDS atomics) ----------------
__global__ __launch_bounds__(256) void ea_bucket(const uint* __restrict__ metab,
                                                 const uint2* __restrict__ eab,
                                                 const uint* __restrict__ base,
                                                 float* __restrict__ EA, int N) {
    __shared__ float eagg[64][5];
    int t = threadIdx.x, k = blockIdx.x;
    for (int i = t; i < 64 * 5; i += 256) ((float*)eagg)[i] = 0.f;
    __syncthreads();
    int e0 = base[k], e1 = base[k + 1];
    for (int e = e0 + t; e < e1; e += 256) {
        uint m = metab[e];
        int dl = (m >> 16) & 63;
        uint2 q = eab[e];
        float2 a = __half22float2(*(__half2*)&q.x);
        float2 c = __half22float2(*(__half2*)&q.y);
        atomicAdd(&eagg[dl][0], a.x);
        atomicAdd(&eagg[dl][1], a.y);
        atomicAdd(&eagg[dl][2], c.x);
        atomicAdd(&eagg[dl][3], c.y);
    }
    __syncthreads();
    if (t < 256) {
        int n = t >> 2, j = t & 3;
        int node = k * 64 + n;
        if (node < N) EA[(size_t)node * 4 + j] = eagg[n][j];
    }
}

// ---------------- bucket conv: LDS-atomic SpMM + dense node update ----------------
template <int FIN>
__global__ __launch_bounds__(256) void conv_bucket(const __half* __restrict__ hin,
                                                   const float4* __restrict__ EA,
                                                   const uint* __restrict__ metab,
                                                   const uint* __restrict__ base,
                                                   const float* __restrict__ Wr,
                                                   const float* __restrict__ Wm,
                                                   const float* __restrict__ bb,
                                                   __half* __restrict__ hout, int N) {
    __shared__ float agg[64][FIN + 1];   // odd stride -> all 32 banks used
    __shared__ float4 ealds[64];
    int t = threadIdx.x, k = blockIdx.x;
    for (int i = t; i < 64 * (FIN + 1); i += 256) ((float*)agg)[i] = 0.f;
    if (t < 64) {
        int node = k * 64 + t;
        ealds[t] = (node < N) ? EA[node] : make_float4(0.f, 0.f, 0.f, 0.f);
    }
    __syncthreads();
    int e0 = base[k], e1 = base[k + 1];
    for (int e = e0 + t; e < e1; e += 256) {
        uint m = metab[e];
        int src = m & 0xffff;
        int dl = (m >> 16) & 63;
        const uint4* hp = (const uint4*)(hin + (size_t)src * FIN);
        #pragma unroll
        for (int j = 0; j < FIN / 8; ++j) {
            uint4 q = hp[j];
            float2 p0 = __half22float2(*(__half2*)&q.x);
            float2 p1 = __half22float2(*(__half2*)&q.y);
            float2 p2 = __half22float2(*(__half2*)&q.z);
            float2 p3 = __half22float2(*(__half2*)&q.w);
            atomicAdd(&agg[dl][j * 8 + 0], p0.x);
            atomicAdd(&agg[dl][j * 8 + 1], p0.y);
            atomicAdd(&agg[dl][j * 8 + 2], p1.x);
            atomicAdd(&agg[dl][j * 8 + 3], p1.y);
            atomicAdd(&agg[dl][j * 8 + 4], p2.x);
            atomicAdd(&agg[dl][j * 8 + 5], p2.y);
            atomicAdd(&agg[dl][j * 8 + 6], p3.x);
            atomicAdd(&agg[dl][j * 8 + 7], p3.y);
        }
    }
    __syncthreads();
    // node update: 64 nodes x 48 feats = 3072 outputs, 12 per thread
    #pragma unroll
    for (int r = 0; r < 12; ++r) {
        int idx = r * 256 + t;
        int n = idx / 48, f = idx - n * 48;
        int node = k * 64 + n;
        if (node < N) {
            float acc = bb[f];
            const __half* hs = hin + (size_t)node * FIN;
            #pragma unroll
            for (int kk = 0; kk < FIN; ++kk)
                acc += __half2float(hs[kk]) * Wr[kk * 48 + f] + agg[n][kk] * Wm[kk * 48 + f];
            float4 ea = ealds[n];
            acc += ea.x * Wm[(FIN + 0) * 48 + f] + ea.y * Wm[(FIN + 1) * 48 + f]
                 + ea.z * Wm[(FIN + 2) * 48 + f] + ea.w * Wm[(FIN + 3) * 48 + f];
            hout[(size_t)node * 48 + f] = __float2half(LRELU(acc));
        }
    }
}

// ---------------- per-graph mean readout (batch is sorted, fp16 h) ----------------
__global__ __launch_bounds__(256) void readout_kernel(const __half* __restrict__ h,
                                                      const int* __restrict__ batch,
                                                      float* __restrict__ hcat, int N, int l) {
    int g = blockIdx.x;
    int lo = 0, hi = N;
    while (lo < hi) { int m = (lo + hi) >> 1; if (batch[m] < g) lo = m + 1; else hi = m; }
    int start = lo;
    hi = N;
    while (lo < hi) { int m = (lo + hi) >> 1; if (batch[m] < g + 1) lo = m + 1; else hi = m; }
    int end = lo;
    __shared__ float sred[4][48];
    int w = threadIdx.x >> 6, lane = threadIdx.x & 63;
    float acc = 0.f;
    if (lane < 48)
        for (int n = start + w; n < end; n += 4) acc += __half2float(h[(size_t)n * 48 + lane]);
    if (lane < 48) sred[w][lane] = acc;
    __syncthreads();
    int t = threadIdx.x;
    if (t < 48) {
        float s = sred[0][t] + sred[1][t] + sred[2][t] + sred[3][t];
        float cnt = (float)(end - start);
        hcat[g * 144 + l * 48 + t] = s / fmaxf(cnt, 1.f);
    }
}

// ---------------- final MLP: one block per graph ----------------
__global__ __launch_bounds__(128) void mlp_kernel(const float* __restrict__ hcat,
                                                  const float* __restrict__ Wl1, const float* __restrict__ bl1,
                                                  const float* __restrict__ Wl2, const float* __restrict__ bl2,
                                                  const float* __restrict__ Wf, const float* __restrict__ bf,
                                                  float* __restrict__ out) {
    int g = blockIdx.x, t = threadIdx.x;
    __shared__ float buf[144];
    __shared__ float l1[128];
    for (int i = t; i < 144; i += 128) buf[i] = hcat[g * 144 + i];
    __syncthreads();
    float acc = bl1[t];
    for (int k = 0; k < 144; ++k) acc += buf[k] * Wl1[k * 128 + t];
    acc = LRELU(acc);
    l1[t] = acc;
    __syncthreads();
    float acc2 = bl2[t];
    for (int k = 0; k < 128; ++k) acc2 += l1[k] * Wl2[k * 128 + t];
    acc2 = LRELU(acc2);
    __syncthreads();
    buf[t] = acc2;
    __syncthreads();
    if (t < 4) {
        float a = bf[t];
        for (int k = 0; k < 128; ++k) a += buf[k] * Wf[k * 4 + t];
        out[g * 4 + t] = a;
    }
}

extern "C" void kernel_launch(void* const* d_in, const int* in_sizes, int n_in,
                              void* d_out, int out_size, void* d_ws, size_t ws_size,
                              hipStream_t stream) {
    const float* x     = (const float*)d_in[0];
    const float* eattr = (const float*)d_in[1];
    const float* Wr0 = (const float*)d_in[2];
    const float* Wm0 = (const float*)d_in[3];
    const float* b0  = (const float*)d_in[4];
    const float* Wr1 = (const float*)d_in[5];
    const float* Wm1 = (const float*)d_in[6];
    const float* b1  = (const float*)d_in[7];
    const float* Wr2 = (const float*)d_in[8];
    const float* Wm2 = (const float*)d_in[9];
    const float* b2  = (const float*)d_in[10];
    const float* Wl1 = (const float*)d_in[11];
    const float* bl1 = (const float*)d_in[12];
    const float* Wl2 = (const float*)d_in[13];
    const float* bl2 = (const float*)d_in[14];
    const float* Wf  = (const float*)d_in[15];
    const float* bf  = (const float*)d_in[16];
    const int* ei    = (const int*)d_in[17];
    const int* batch = (const int*)d_in[18];

    int N = in_sizes[0] / 16;
    int E = in_sizes[1] / 4;
    int NB = (N + BWN - 1) / BWN;       // buckets (<=1024 for N<=65536)
    int NBLK = (E + EPB - 1) / EPB;     // bucketing blocks

    // ---- workspace layout (16B-aligned first) ----
    char* p = (char*)d_ws;
    float4* EA   = (float4*)p;                    p += (size_t)N * 16;
    uint2* eab   = (uint2*)p;                     p += (size_t)E * 8;
    __half* xn   = (__half*)p;                    p += (size_t)N * 16 * 2;
    __half* h16a = (__half*)p;                    p += (size_t)N * 48 * 2;
    __half* h16b = (__half*)p;                    p += (size_t)N * 48 * 2;
    uint* metab  = (uint*)p;                      p += (size_t)E * 4;
    uint* cnt    = (uint*)p;                      p += (size_t)NBLK * NB * 4;
    uint* total  = (uint*)p;                      p += (size_t)NB * 4;
    uint* base   = (uint*)p;                      p += (size_t)(NB + 1) * 4;
    float* estats = (float*)p;                    p += 8 * 4;
    float* xstats = (float*)p;                    p += 32 * 4;
    float* hcat   = (float*)p;                    p += 64 * 144 * 4;

    hipMemsetAsync(estats, 0, 40 * sizeof(float), stream);   // estats + xstats

    int n4 = N * 4;  // float4 count of x
    xstats_kernel<<<256, 256, 0, stream>>>((const float4*)x, xstats, n4);
    xnorm_kernel<<<256, 256, 0, stream>>>((const float4*)x, (__half2*)xn, xstats, n4, 1.f / N);
    estats_kernel<<<1024, 256, 0, stream>>>((const float4*)eattr, estats, E);
    histA<<<NBLK, 256, 0, stream>>>(ei + E, cnt, E, NB);
    scanB<<<NB, 256, 0, stream>>>(cnt, total, NBLK, NB);
    scanB2<<<1, 256, 0, stream>>>(total, base, NB);
    scatterC<<<NBLK, 256, 0, stream>>>(ei, (const float4*)eattr, cnt, base, estats,
                                       metab, eab, E, NB, 1.f / E);
    ea_bucket<<<NB, 256, 0, stream>>>(metab, eab, base, (float*)EA, N);

    conv_bucket<16><<<NB, 256, 0, stream>>>(xn, EA, metab, base, Wr0, Wm0, b0, h16a, N);
    readout_kernel<<<64, 256, 0, stream>>>(h16a, batch, hcat, N, 0);
    conv_bucket<48><<<NB, 256, 0, stream>>>(h16a, EA, metab, base, Wr1, Wm1, b1, h16b, N);
    readout_kernel<<<64, 256, 0, stream>>>(h16b, batch, hcat, N, 1);
    conv_bucket<48><<<NB, 256, 0, stream>>>(h16b, EA, metab, base, Wr2, Wm2, b2, h16a, N);
    readout_kernel<<<64, 256, 0, stream>>>(h16a, batch, hcat, N, 2);

    mlp_kernel<<<64, 128, 0, stream>>>(hcat, Wl1, bl1, Wl2, bl2, Wf, bf, (float*)d_out);
}

// Round 7
// 591.659 us; speedup vs baseline: 2.8634x; 2.8634x over previous
//
#include <hip/hip_runtime.h>
#include <hip/hip_bf16.h>
#include <hip/hip_fp16.h>

#define LRELU(v) ((v) >= 0.f ? (v) : 0.2f * (v))

typedef unsigned int uint;

static const int EPB = 2048;   // edges per bucketing block
static const int BWN = 64;     // nodes per bucket (dst >> 6)

// ---------------- feature-norm stats for x ----------------
__global__ __launch_bounds__(256) void xstats_kernel(const float4* __restrict__ x4,
                                                     float* __restrict__ xstats, int n4) {
    __shared__ float ls[32];
    if (threadIdx.x < 32) ls[threadIdx.x] = 0.f;
    __syncthreads();
    float s1[4] = {0,0,0,0}, s2[4] = {0,0,0,0};
    int stride = gridDim.x * blockDim.x;
    int j4 = (threadIdx.x & 3) * 4;  // stride % 4 == 0 -> constant per thread
    for (int i = blockIdx.x * blockDim.x + threadIdx.x; i < n4; i += stride) {
        float4 v = x4[i];
        s1[0] += v.x; s2[0] += v.x * v.x;
        s1[1] += v.y; s2[1] += v.y * v.y;
        s1[2] += v.z; s2[2] += v.z * v.z;
        s1[3] += v.w; s2[3] += v.w * v.w;
    }
    #pragma unroll
    for (int k = 0; k < 4; ++k) {
        atomicAdd(&ls[j4 + k], s1[k]);
        atomicAdd(&ls[16 + j4 + k], s2[k]);
    }
    __syncthreads();
    if (threadIdx.x < 32) atomicAdd(&xstats[threadIdx.x], ls[threadIdx.x]);
}

// normalize x and store as fp16
__global__ __launch_bounds__(256) void xnorm_kernel(const float4* __restrict__ x4,
                                                    __half2* __restrict__ xn2,
                                                    const float* __restrict__ xstats,
                                                    int n4, float invN) {
    int stride = gridDim.x * blockDim.x;
    for (int i = blockIdx.x * blockDim.x + threadIdx.x; i < n4; i += stride) {
        int j4 = (i & 3) * 4;
        float4 v = x4[i];
        float o[4], in[4] = {v.x, v.y, v.z, v.w};
        #pragma unroll
        for (int k = 0; k < 4; ++k) {
            float mu = xstats[j4 + k] * invN;
            float var = xstats[16 + j4 + k] * invN - mu * mu;
            o[k] = (in[k] - mu) * rsqrtf(var + 1e-5f);
        }
        xn2[2 * i]     = __floats2half2_rn(o[0], o[1]);
        xn2[2 * i + 1] = __floats2half2_rn(o[2], o[3]);
    }
}

// ---------------- edge-attr stats (fp32) ----------------
__global__ __launch_bounds__(256) void estats_kernel(const float4* __restrict__ e4,
                                                     float* __restrict__ estats, int E) {
    __shared__ float ls[8];
    if (threadIdx.x < 8) ls[threadIdx.x] = 0.f;
    __syncthreads();
    float s1[4] = {0,0,0,0}, s2[4] = {0,0,0,0};
    int stride = gridDim.x * blockDim.x;
    for (int e = blockIdx.x * blockDim.x + threadIdx.x; e < E; e += stride) {
        float4 v = e4[e];
        s1[0] += v.x; s2[0] += v.x * v.x;
        s1[1] += v.y; s2[1] += v.y * v.y;
        s1[2] += v.z; s2[2] += v.z * v.z;
        s1[3] += v.w; s2[3] += v.w * v.w;
    }
    #pragma unroll
    for (int k = 0; k < 4; ++k) {
        atomicAdd(&ls[k], s1[k]);
        atomicAdd(&ls[4 + k], s2[k]);
    }
    __syncthreads();
    if (threadIdx.x < 8) atomicAdd(&estats[threadIdx.x], ls[threadIdx.x]);
}

// ---------------- bucket histogram: cnt[block][bucket] (no global atomics) ----------------
__global__ __launch_bounds__(256) void histA(const int* __restrict__ ei_dst,
                                             uint* __restrict__ cnt, int E, int NB) {
    __shared__ uint hist[1024];
    int t = threadIdx.x, b = blockIdx.x;
    for (int i = t; i < NB; i += 256) hist[i] = 0;
    __syncthreads();
    int e0 = b * EPB, e1 = min(e0 + EPB, E);
    for (int e = e0 + t; e < e1; e += 256)
        atomicAdd(&hist[ei_dst[e] >> 6], 1u);
    __syncthreads();
    for (int i = t; i < NB; i += 256) cnt[(size_t)b * NB + i] = hist[i];
}

// ---------------- scan cnt columns in place: cnt[b][k] <- sum_{b'<b} cnt[b'][k]; total[k] ----------------
__global__ __launch_bounds__(256) void scanB(uint* __restrict__ cnt,
                                             uint* __restrict__ total, int NBLK, int NB) {
    int k = blockIdx.x;
    int t = threadIdx.x, lane = t & 63, w = t >> 6;
    __shared__ uint wsum[4], woff[4], ctot;
    uint carry = 0;
    int chunks = (NBLK + 255) >> 8;
    for (int c = 0; c < chunks; ++c) {
        int b = (c << 8) + t;
        uint v = (b < NBLK) ? cnt[(size_t)b * NB + k] : 0u;
        uint inc = v;
        #pragma unroll
        for (int d = 1; d < 64; d <<= 1) {
            uint u = __shfl_up(inc, d);
            if (lane >= d) inc += u;
        }
        if (lane == 63) wsum[w] = inc;
        __syncthreads();
        if (t == 0) {
            uint s = 0;
            #pragma unroll
            for (int i = 0; i < 4; ++i) { woff[i] = s; s += wsum[i]; }
            ctot = s;
        }
        __syncthreads();
        if (b < NBLK) cnt[(size_t)b * NB + k] = carry + woff[w] + inc - v;
        carry += ctot;
        __syncthreads();
    }
    if (t == 0) total[k] = carry;
}

// ---------------- exclusive scan of bucket totals -> base[NB+1] ----------------
__global__ __launch_bounds__(256) void scanB2(const uint* __restrict__ total,
                                              uint* __restrict__ base, int NB) {
    int t = threadIdx.x, lane = t & 63, w = t >> 6;
    __shared__ uint wsum[4], woff[4], ctot;
    uint carry = 0;
    int chunks = (NB + 255) >> 8;
    for (int c = 0; c < chunks; ++c) {
        int k = (c << 8) + t;
        uint v = (k < NB) ? total[k] : 0u;
        uint inc = v;
        #pragma unroll
        for (int d = 1; d < 64; d <<= 1) {
            uint u = __shfl_up(inc, d);
            if (lane >= d) inc += u;
        }
        if (lane == 63) wsum[w] = inc;
        __syncthreads();
        if (t == 0) {
            uint s = 0;
            #pragma unroll
            for (int i = 0; i < 4; ++i) { woff[i] = s; s += wsum[i]; }
            ctot = s;
        }
        __syncthreads();
        if (k < NB) base[k] = carry + woff[w] + inc - v;
        carry += ctot;
        __syncthreads();
    }
    if (t == 0) base[NB] = carry;
}

// ---------------- bucket-grouped scatter (no global atomics; disjoint ranges) ----------------
// metab[pos] = src | (dst&63)<<16 ; eab[pos] = fp16x4 of featnorm'd eattr
__global__ __launch_bounds__(256) void scatterC(const int* __restrict__ ei,
                                                const float4* __restrict__ eattr,
                                                const uint* __restrict__ cnt,
                                                const uint* __restrict__ base,
                                                const float* __restrict__ estats,
                                                uint* __restrict__ metab,
                                                uint2* __restrict__ eab,
                                                int E, int NB, float invE) {
    __shared__ uint cur[1024];
    int t = threadIdx.x, b = blockIdx.x;
    for (int i = t; i < NB; i += 256)
        cur[i] = base[i] + cnt[(size_t)b * NB + i];
    float mu[4], rs[4];
    #pragma unroll
    for (int j = 0; j < 4; ++j) {
        mu[j] = estats[j] * invE;
        float var = estats[4 + j] * invE - mu[j] * mu[j];
        rs[j] = rsqrtf(var + 1e-5f);
    }
    __syncthreads();
    int e0 = b * EPB, e1 = min(e0 + EPB, E);
    for (int e = e0 + t; e < e1; e += 256) {
        int src = ei[e];
        int dst = ei[E + e];
        float4 v = eattr[e];
        uint pos = atomicAdd(&cur[dst >> 6], 1u);
        metab[pos] = (uint)src | ((uint)(dst & 63) << 16);
        uint2 q;
        *(__half2*)&q.x = __floats2half2_rn((v.x - mu[0]) * rs[0], (v.y - mu[1]) * rs[1]);
        *(__half2*)&q.y = __floats2half2_rn((v.z - mu[2]) * rs[2], (v.w - mu[3]) * rs[3]);
        eab[pos] = q;
    }
}

// ---------------- in-bucket counting sort -> full dst-sorted CSR + node offsets ----------------
__global__ __launch_bounds__(256) void sort2(const uint* __restrict__ metab,
                                             const uint2* __restrict__ eab,
                                             const uint* __restrict__ base,
                                             uint* __restrict__ src_sorted,
                                             uint2* __restrict__ ea_sorted,
                                             int* __restrict__ offs, int N, int E) {
    __shared__ uint hist[64], excl[64], cur[64];
    int t = threadIdx.x, k = blockIdx.x;
    if (t < 64) hist[t] = 0;
    __syncthreads();
    int e0 = base[k], e1 = base[k + 1];
    for (int e = e0 + t; e < e1; e += 256)
        atomicAdd(&hist[(metab[e] >> 16) & 63], 1u);
    __syncthreads();
    if (t < 64) {                       // wave-scan of 64 counters (first wave)
        uint v = hist[t];
        uint inc = v;
        #pragma unroll
        for (int d = 1; d < 64; d <<= 1) {
            uint u = __shfl_up(inc, d);
            if (t >= d) inc += u;
        }
        excl[t] = inc - v;
        cur[t] = inc - v;
        int node = k * 64 + t;
        if (node < N) offs[node] = (int)(e0 + inc - v);
    }
    if (t == 0 && k == 0) offs[N] = E;
    __syncthreads();
    for (int e = e0 + t; e < e1; e += 256) {
        uint m = metab[e];
        int dl = (m >> 16) & 63;
        uint pos = e0 + atomicAdd(&cur[dl], 1u);
        src_sorted[pos] = m & 0xffffu;
        ea_sorted[pos] = eab[e];
    }
}

// ---------------- per-node edge-attr segment sum (featnorm already folded) ----------------
__global__ __launch_bounds__(256) void ea_sum(const uint2* __restrict__ ea_sorted,
                                              const int* __restrict__ offs,
                                              float4* __restrict__ EA, int N) {
    int g = threadIdx.x >> 4, gl = threadIdx.x & 15;
    int node = blockIdx.x * 16 + g;
    if (node >= N) return;
    int s0 = offs[node], s1 = offs[node + 1];
    float4 acc = make_float4(0.f, 0.f, 0.f, 0.f);
    for (int e = s0 + gl; e < s1; e += 16) {
        uint2 q = ea_sorted[e];
        float2 a = __half22float2(*(__half2*)&q.x);
        float2 c = __half22float2(*(__half2*)&q.y);
        acc.x += a.x; acc.y += a.y; acc.z += c.x; acc.w += c.y;
    }
    #pragma unroll
    for (int d = 1; d < 16; d <<= 1) {
        acc.x += __shfl_xor(acc.x, d);
        acc.y += __shfl_xor(acc.y, d);
        acc.z += __shfl_xor(acc.z, d);
        acc.w += __shfl_xor(acc.w, d);
    }
    if (gl == 0) EA[node] = acc;
}

// ---------------- fused conv layer: fp16 CSR gather + node update ----------------
// one wave per node; 8 groups of 8 lanes; group = edge slot, lane%8 = half2 feature pair
template <int FIN>
__global__ __launch_bounds__(256) void conv_kernel(const __half* __restrict__ hin,
                                                   const float4* __restrict__ EA,
                                                   const int* __restrict__ offs,
                                                   const uint* __restrict__ src_sorted,
                                                   const float* __restrict__ Wr,
                                                   const float* __restrict__ Wm,
                                                   const float* __restrict__ b,
                                                   __half* __restrict__ hout, int N) {
    __shared__ float gbuf[4][48];
    __shared__ float hbuf[4][48];
    int w = threadIdx.x >> 6;
    int lane = threadIdx.x & 63;
    int node = blockIdx.x * 4 + w;
    if (node < N) {
        int s0 = offs[node], s1 = offs[node + 1];
        int g = lane >> 3, j = lane & 7;
        float2 a0 = {0.f, 0.f}, a1 = {0.f, 0.f}, a2 = {0.f, 0.f};
        for (int e = s0 + g; e < s1; e += 8) {
            int s = (int)src_sorted[e];
            const __half2* hp = (const __half2*)(hin + (size_t)s * FIN);
            float2 v0 = __half22float2(hp[j]);
            a0.x += v0.x; a0.y += v0.y;
            if (FIN > 16) {
                float2 v1 = __half22float2(hp[8 + j]);
                float2 v2 = __half22float2(hp[16 + j]);
                a1.x += v1.x; a1.y += v1.y;
                a2.x += v2.x; a2.y += v2.y;
            }
        }
        #pragma unroll
        for (int m = 8; m < 64; m <<= 1) {
            a0.x += __shfl_xor(a0.x, m); a0.y += __shfl_xor(a0.y, m);
            if (FIN > 16) {
                a1.x += __shfl_xor(a1.x, m); a1.y += __shfl_xor(a1.y, m);
                a2.x += __shfl_xor(a2.x, m); a2.y += __shfl_xor(a2.y, m);
            }
        }
        if (g == 0) {
            gbuf[w][2 * j] = a0.x; gbuf[w][2 * j + 1] = a0.y;
            if (FIN > 16) {
                gbuf[w][16 + 2 * j] = a1.x; gbuf[w][17 + 2 * j] = a1.y;
                gbuf[w][32 + 2 * j] = a2.x; gbuf[w][33 + 2 * j] = a2.y;
            }
        }
        if (lane < FIN) hbuf[w][lane] = __half2float(hin[(size_t)node * FIN + lane]);
    }
    __syncthreads();
    if (node < N && lane < 48) {
        int f = lane;
        float acc = b[f];
        #pragma unroll
        for (int k = 0; k < FIN; ++k)
            acc += hbuf[w][k] * Wr[k * 48 + f] + gbuf[w][k] * Wm[k * 48 + f];
        float4 ea = EA[node];
        acc += ea.x * Wm[(FIN + 0) * 48 + f] + ea.y * Wm[(FIN + 1) * 48 + f]
             + ea.z * Wm[(FIN + 2) * 48 + f] + ea.w * Wm[(FIN + 3) * 48 + f];
        hout[(size_t)node * 48 + f] = __float2half(LRELU(acc));
    }
}

// ---------------- per-graph mean readout (batch is sorted, fp16 h) ----------------
__global__ __launch_bounds__(256) void readout_kernel(const __half* __restrict__ h,
                                                      const int* __restrict__ batch,
                                                      float* __restrict__ hcat, int N, int l) {
    int g = blockIdx.x;
    int lo = 0, hi = N;
    while (lo < hi) { int m = (lo + hi) >> 1; if (batch[m] < g) lo = m + 1; else hi = m; }
    int start = lo;
    hi = N;
    while (lo < hi) { int m = (lo + hi) >> 1; if (batch[m] < g + 1) lo = m + 1; else hi = m; }
    int end = lo;
    __shared__ float sred[4][48];
    int w = threadIdx.x >> 6, lane = threadIdx.x & 63;
    float acc = 0.f;
    if (lane < 48)
        for (int n = start + w; n < end; n += 4) acc += __half2float(h[(size_t)n * 48 + lane]);
    if (lane < 48) sred[w][lane] = acc;
    __syncthreads();
    int t = threadIdx.x;
    if (t < 48) {
        float s = sred[0][t] + sred[1][t] + sred[2][t] + sred[3][t];
        float cnt = (float)(end - start);
        hcat[g * 144 + l * 48 + t] = s / fmaxf(cnt, 1.f);
    }
}

// ---------------- final MLP: one block per graph ----------------
__global__ __launch_bounds__(128) void mlp_kernel(const float* __restrict__ hcat,
                                                  const float* __restrict__ Wl1, const float* __restrict__ bl1,
                                                  const float* __restrict__ Wl2, const float* __restrict__ bl2,
                                                  const float* __restrict__ Wf, const float* __restrict__ bf,
                                                  float* __restrict__ out) {
    int g = blockIdx.x, t = threadIdx.x;
    __shared__ float buf[144];
    __shared__ float l1[128];
    for (int i = t; i < 144; i += 128) buf[i] = hcat[g * 144 + i];
    __syncthreads();
    float acc = bl1[t];
    for (int k = 0; k < 144; ++k) acc += buf[k] * Wl1[k * 128 + t];
    acc = LRELU(acc);
    l1[t] = acc;
    __syncthreads();
    float acc2 = bl2[t];
    for (int k = 0; k < 128; ++k) acc2 += l1[k] * Wl2[k * 128 + t];
    acc2 = LRELU(acc2);
    __syncthreads();
    buf[t] = acc2;
    __syncthreads();
    if (t < 4) {
        float a = bf[t];
        for (int k = 0; k < 128; ++k) a += buf[k] * Wf[k * 4 + t];
        out[g * 4 + t] = a;
    }
}

extern "C" void kernel_launch(void* const* d_in, const int* in_sizes, int n_in,
                              void* d_out, int out_size, void* d_ws, size_t ws_size,
                              hipStream_t stream) {
    const float* x     = (const float*)d_in[0];
    const float* eattr = (const float*)d_in[1];
    const float* Wr0 = (const float*)d_in[2];
    const float* Wm0 = (const float*)d_in[3];
    const float* b0  = (const float*)d_in[4];
    const float* Wr1 = (const float*)d_in[5];
    const float* Wm1 = (const float*)d_in[6];
    const float* b1  = (const float*)d_in[7];
    const float* Wr2 = (const float*)d_in[8];
    const float* Wm2 = (const float*)d_in[9];
    const float* b2  = (const float*)d_in[10];
    const float* Wl1 = (const float*)d_in[11];
    const float* bl1 = (const float*)d_in[12];
    const float* Wl2 = (const float*)d_in[13];
    const float* bl2 = (const float*)d_in[14];
    const float* Wf  = (const float*)d_in[15];
    const float* bf  = (const float*)d_in[16];
    const int* ei    = (const int*)d_in[17];
    const int* batch = (const int*)d_in[18];

    int N = in_sizes[0] / 16;
    int E = in_sizes[1] / 4;
    int NB = (N + BWN - 1) / BWN;       // buckets (<=1024 for N<=65536)
    int NBLK = (E + EPB - 1) / EPB;     // bucketing blocks

    // ---- workspace layout (16B-aligned first) ----
    char* p = (char*)d_ws;
    float4* EA     = (float4*)p;                  p += (size_t)N * 16;
    uint2* eab     = (uint2*)p;                   p += (size_t)E * 8;
    uint2* ea_sorted = (uint2*)p;                 p += (size_t)E * 8;
    __half* xn   = (__half*)p;                    p += (size_t)N * 16 * 2;
    __half* h16a = (__half*)p;                    p += (size_t)N * 48 * 2;
    __half* h16b = (__half*)p;                    p += (size_t)N * 48 * 2;
    uint* metab  = (uint*)p;                      p += (size_t)E * 4;
    uint* src_sorted = (uint*)p;                  p += (size_t)E * 4;
    uint* cnt    = (uint*)p;                      p += (size_t)NBLK * NB * 4;
    uint* total  = (uint*)p;                      p += (size_t)NB * 4;
    uint* base   = (uint*)p;                      p += (size_t)(NB + 1) * 4;
    int*  offs   = (int*)p;                       p += (size_t)(N + 1) * 4;
    float* estats = (float*)p;                    p += 8 * 4;
    float* xstats = (float*)p;                    p += 32 * 4;
    float* hcat   = (float*)p;                    p += 64 * 144 * 4;

    hipMemsetAsync(estats, 0, 40 * sizeof(float), stream);   // estats + xstats

    int n4 = N * 4;  // float4 count of x
    xstats_kernel<<<256, 256, 0, stream>>>((const float4*)x, xstats, n4);
    xnorm_kernel<<<256, 256, 0, stream>>>((const float4*)x, (__half2*)xn, xstats, n4, 1.f / N);
    estats_kernel<<<1024, 256, 0, stream>>>((const float4*)eattr, estats, E);
    histA<<<NBLK, 256, 0, stream>>>(ei + E, cnt, E, NB);
    scanB<<<NB, 256, 0, stream>>>(cnt, total, NBLK, NB);
    scanB2<<<1, 256, 0, stream>>>(total, base, NB);
    scatterC<<<NBLK, 256, 0, stream>>>(ei, (const float4*)eattr, cnt, base, estats,
                                       metab, eab, E, NB, 1.f / E);
    sort2<<<NB, 256, 0, stream>>>(metab, eab, base, src_sorted, ea_sorted, offs, N, E);
    ea_sum<<<(N + 15) / 16, 256, 0, stream>>>(ea_sorted, offs, EA, N);

    conv_kernel<16><<<(N + 3) / 4, 256, 0, stream>>>(xn, EA, offs, src_sorted, Wr0, Wm0, b0, h16a, N);
    readout_kernel<<<64, 256, 0, stream>>>(h16a, batch, hcat, N, 0);
    conv_kernel<48><<<(N + 3) / 4, 256, 0, stream>>>(h16a, EA, offs, src_sorted, Wr1, Wm1, b1, h16b, N);
    readout_kernel<<<64, 256, 0, stream>>>(h16b, batch, hcat, N, 1);
    conv_kernel<48><<<(N + 3) / 4, 256, 0, stream>>>(h16b, EA, offs, src_sorted, Wr2, Wm2, b2, h16a, N);
    readout_kernel<<<64, 256, 0, stream>>>(h16a, batch, hcat, N, 2);

    mlp_kernel<<<64, 128, 0, stream>>>(hcat, Wl1, bl1, Wl2, bl2, Wf, bf, (float*)d_out);
}

// Round 8
// 428.235 us; speedup vs baseline: 3.9561x; 1.3816x over previous
//
#include <hip/hip_runtime.h>
#include <hip/hip_bf16.h>
#include <hip/hip_fp16.h>

#define LRELU(v) ((v) >= 0.f ? (v) : 0.2f * (v))

typedef unsigned int uint;

static const int EPB = 2048;   // edges per bucketing block
static const int BWN = 64;     // nodes per bucket (dst >> 6)
static const int NXB = 256;    // xstats role blocks
static const int NEB = 1024;   // estats role blocks
static const int NRB = 512;    // readout blocks

__device__ inline __half2 shfl_xor_h2(__half2 v, int m) {
    int i = *(int*)&v;
    i = __shfl_xor(i, m);
    return *(__half2*)&i;
}

// ---------------- pass1: fused xstats + estats + bucket histogram ----------------
__global__ __launch_bounds__(256) void pass1(const float4* __restrict__ x4, int n4,
                                             const float4* __restrict__ e4, int E,
                                             const int* __restrict__ ei_dst,
                                             float* __restrict__ xstats,
                                             float* __restrict__ estats,
                                             uint* __restrict__ cnt, int NB) {
    __shared__ float ls[32];
    __shared__ uint hist[1024];
    int t = threadIdx.x, b = blockIdx.x;
    if (b < NXB) {                       // ---- x stats ----
        if (t < 32) ls[t] = 0.f;
        __syncthreads();
        float s1[4] = {0,0,0,0}, s2[4] = {0,0,0,0};
        int j4 = (t & 3) * 4;            // stride 65536 % 4 == 0
        for (int i = b * 256 + t; i < n4; i += NXB * 256) {
            float4 v = x4[i];
            s1[0] += v.x; s2[0] += v.x * v.x;
            s1[1] += v.y; s2[1] += v.y * v.y;
            s1[2] += v.z; s2[2] += v.z * v.z;
            s1[3] += v.w; s2[3] += v.w * v.w;
        }
        #pragma unroll
        for (int k = 0; k < 4; ++k) {
            atomicAdd(&ls[j4 + k], s1[k]);
            atomicAdd(&ls[16 + j4 + k], s2[k]);
        }
        __syncthreads();
        if (t < 32) atomicAdd(&xstats[t], ls[t]);
    } else if (b < NXB + NEB) {          // ---- eattr stats ----
        if (t < 8) ls[t] = 0.f;
        __syncthreads();
        float s1[4] = {0,0,0,0}, s2[4] = {0,0,0,0};
        for (int e = (b - NXB) * 256 + t; e < E; e += NEB * 256) {
            float4 v = e4[e];
            s1[0] += v.x; s2[0] += v.x * v.x;
            s1[1] += v.y; s2[1] += v.y * v.y;
            s1[2] += v.z; s2[2] += v.z * v.z;
            s1[3] += v.w; s2[3] += v.w * v.w;
        }
        #pragma unroll
        for (int k = 0; k < 4; ++k) {
            atomicAdd(&ls[k], s1[k]);
            atomicAdd(&ls[4 + k], s2[k]);
        }
        __syncthreads();
        if (t < 8) atomicAdd(&estats[t], ls[t]);
    } else {                             // ---- bucket histogram ----
        int hb = b - NXB - NEB;
        for (int i = t; i < NB; i += 256) hist[i] = 0;
        __syncthreads();
        int e0 = hb * EPB, e1 = min(e0 + EPB, E);
        for (int e = e0 + t; e < e1; e += 256)
            atomicAdd(&hist[ei_dst[e] >> 6], 1u);
        __syncthreads();
        for (int i = t; i < NB; i += 256) cnt[(size_t)hb * NB + i] = hist[i];
    }
}

// normalize x and store as fp16 (rows of 16)
__global__ __launch_bounds__(256) void xnorm_kernel(const float4* __restrict__ x4,
                                                    __half2* __restrict__ xn2,
                                                    const float* __restrict__ xstats,
                                                    int n4, float invN) {
    int stride = gridDim.x * blockDim.x;
    for (int i = blockIdx.x * blockDim.x + threadIdx.x; i < n4; i += stride) {
        int j4 = (i & 3) * 4;
        float4 v = x4[i];
        float o[4], in[4] = {v.x, v.y, v.z, v.w};
        #pragma unroll
        for (int k = 0; k < 4; ++k) {
            float mu = xstats[j4 + k] * invN;
            float var = xstats[16 + j4 + k] * invN - mu * mu;
            o[k] = (in[k] - mu) * rsqrtf(var + 1e-5f);
        }
        xn2[2 * i]     = __floats2half2_rn(o[0], o[1]);
        xn2[2 * i + 1] = __floats2half2_rn(o[2], o[3]);
    }
}

// ---------------- scan cnt columns in place; total[k] ----------------
__global__ __launch_bounds__(256) void scanB(uint* __restrict__ cnt,
                                             uint* __restrict__ total, int NBLK, int NB) {
    int k = blockIdx.x;
    int t = threadIdx.x, lane = t & 63, w = t >> 6;
    __shared__ uint wsum[4], woff[4], ctot;
    uint carry = 0;
    int chunks = (NBLK + 255) >> 8;
    for (int c = 0; c < chunks; ++c) {
        int b = (c << 8) + t;
        uint v = (b < NBLK) ? cnt[(size_t)b * NB + k] : 0u;
        uint inc = v;
        #pragma unroll
        for (int d = 1; d < 64; d <<= 1) {
            uint u = __shfl_up(inc, d);
            if (lane >= d) inc += u;
        }
        if (lane == 63) wsum[w] = inc;
        __syncthreads();
        if (t == 0) {
            uint s = 0;
            #pragma unroll
            for (int i = 0; i < 4; ++i) { woff[i] = s; s += wsum[i]; }
            ctot = s;
        }
        __syncthreads();
        if (b < NBLK) cnt[(size_t)b * NB + k] = carry + woff[w] + inc - v;
        carry += ctot;
        __syncthreads();
    }
    if (t == 0) total[k] = carry;
}

// ---------------- scan totals -> base; + per-graph inverse counts ----------------
__global__ __launch_bounds__(256) void scanB2(const uint* __restrict__ total,
                                              uint* __restrict__ base, int NB,
                                              const int* __restrict__ batch, int N,
                                              float* __restrict__ invcnt) {
    int t = threadIdx.x, lane = t & 63, w = t >> 6;
    __shared__ uint wsum[4], woff[4], ctot;
    uint carry = 0;
    int chunks = (NB + 255) >> 8;
    for (int c = 0; c < chunks; ++c) {
        int k = (c << 8) + t;
        uint v = (k < NB) ? total[k] : 0u;
        uint inc = v;
        #pragma unroll
        for (int d = 1; d < 64; d <<= 1) {
            uint u = __shfl_up(inc, d);
            if (lane >= d) inc += u;
        }
        if (lane == 63) wsum[w] = inc;
        __syncthreads();
        if (t == 0) {
            uint s = 0;
            #pragma unroll
            for (int i = 0; i < 4; ++i) { woff[i] = s; s += wsum[i]; }
            ctot = s;
        }
        __syncthreads();
        if (k < NB) base[k] = carry + woff[w] + inc - v;
        carry += ctot;
        __syncthreads();
    }
    if (t == 0) base[NB] = carry;
    if (t < 64) {                       // per-graph counts via binary search
        int g = t;
        int lo = 0, hi = N;
        while (lo < hi) { int m = (lo + hi) >> 1; if (batch[m] < g) lo = m + 1; else hi = m; }
        int start = lo;
        hi = N;
        while (lo < hi) { int m = (lo + hi) >> 1; if (batch[m] < g + 1) lo = m + 1; else hi = m; }
        invcnt[g] = 1.f / fmaxf((float)(lo - start), 1.f);
    }
}

// ---------------- bucket-grouped scatter (no global atomics) ----------------
__global__ __launch_bounds__(256) void scatterC(const int* __restrict__ ei,
                                                const float4* __restrict__ eattr,
                                                const uint* __restrict__ cnt,
                                                const uint* __restrict__ base,
                                                const float* __restrict__ estats,
                                                uint* __restrict__ metab,
                                                uint2* __restrict__ eab,
                                                int E, int NB, float invE) {
    __shared__ uint cur[1024];
    int t = threadIdx.x, b = blockIdx.x;
    for (int i = t; i < NB; i += 256)
        cur[i] = base[i] + cnt[(size_t)b * NB + i];
    float mu[4], rs[4];
    #pragma unroll
    for (int j = 0; j < 4; ++j) {
        mu[j] = estats[j] * invE;
        float var = estats[4 + j] * invE - mu[j] * mu[j];
        rs[j] = rsqrtf(var + 1e-5f);
    }
    __syncthreads();
    int e0 = b * EPB, e1 = min(e0 + EPB, E);
    for (int e = e0 + t; e < e1; e += 256) {
        int src = ei[e];
        int dst = ei[E + e];
        float4 v = eattr[e];
        uint pos = atomicAdd(&cur[dst >> 6], 1u);
        metab[pos] = (uint)src | ((uint)(dst & 63) << 16);
        uint2 q;
        *(__half2*)&q.x = __floats2half2_rn((v.x - mu[0]) * rs[0], (v.y - mu[1]) * rs[1]);
        *(__half2*)&q.y = __floats2half2_rn((v.z - mu[2]) * rs[2], (v.w - mu[3]) * rs[3]);
        eab[pos] = q;
    }
}

// ---------------- in-bucket counting sort -> CSR + offs + fused EA segment sum ----------------
__global__ __launch_bounds__(256) void sort2(const uint* __restrict__ metab,
                                             const uint2* __restrict__ eab,
                                             const uint* __restrict__ base,
                                             uint* __restrict__ src_sorted,
                                             uint2* __restrict__ ea_sorted,
                                             int* __restrict__ offs,
                                             float4* __restrict__ EA, int N, int E) {
    __shared__ uint hist[64], excl[64], cur[64];
    int t = threadIdx.x, k = blockIdx.x;
    if (t < 64) hist[t] = 0;
    __syncthreads();
    int e0 = base[k], e1 = base[k + 1];
    for (int e = e0 + t; e < e1; e += 256)
        atomicAdd(&hist[(metab[e] >> 16) & 63], 1u);
    __syncthreads();
    if (t < 64) {
        uint v = hist[t];
        uint inc = v;
        #pragma unroll
        for (int d = 1; d < 64; d <<= 1) {
            uint u = __shfl_up(inc, d);
            if (t >= d) inc += u;
        }
        excl[t] = inc - v;
        cur[t] = inc - v;
        int node = k * 64 + t;
        if (node < N) offs[node] = (int)(e0 + inc - v);
    }
    if (t == 0 && k == 0) offs[N] = E;
    __syncthreads();
    for (int e = e0 + t; e < e1; e += 256) {
        uint m = metab[e];
        int dl = (m >> 16) & 63;
        uint pos = e0 + atomicAdd(&cur[dl], 1u);
        src_sorted[pos] = m & 0xffffu;
        ea_sorted[pos] = eab[e];
    }
    __syncthreads();
    // fused EA: 4 lanes per node
    int dl = t >> 2, q = t & 3;
    int node = k * 64 + dl;
    int s0 = e0 + (int)excl[dl], s1 = e0 + (int)cur[dl];
    float4 acc = make_float4(0.f, 0.f, 0.f, 0.f);
    for (int e = s0 + q; e < s1; e += 4) {
        uint2 v = ea_sorted[e];
        float2 a = __half22float2(*(__half2*)&v.x);
        float2 c = __half22float2(*(__half2*)&v.y);
        acc.x += a.x; acc.y += a.y; acc.z += c.x; acc.w += c.y;
    }
    #pragma unroll
    for (int d = 1; d < 4; d <<= 1) {
        acc.x += __shfl_xor(acc.x, d);
        acc.y += __shfl_xor(acc.y, d);
        acc.z += __shfl_xor(acc.z, d);
        acc.w += __shfl_xor(acc.w, d);
    }
    if (q == 0 && node < N) EA[node] = acc;
}

// ---------------- fused conv layer: packed-fp16 CSR gather + node update ----------------
// one wave per node; 8 groups of 8 lanes; group = edge slot
// FIN=16: rows of 16 halves, lane j loads one half2
// FIN=48: rows padded to 64 halves (128 B), lane j loads one uint4 (4x half2)
template <int FIN, int LDI>
__global__ __launch_bounds__(256) void conv_kernel(const __half* __restrict__ hin,
                                                   const float4* __restrict__ EA,
                                                   const int* __restrict__ offs,
                                                   const uint* __restrict__ src_sorted,
                                                   const float* __restrict__ Wr,
                                                   const float* __restrict__ Wm,
                                                   const float* __restrict__ b,
                                                   __half* __restrict__ hout, int N) {
    __shared__ float gbuf[4][48];
    __shared__ float hbuf[4][48];
    int w = threadIdx.x >> 6;
    int lane = threadIdx.x & 63;
    int node = blockIdx.x * 4 + w;
    if (node < N) {
        int s0 = offs[node], s1 = offs[node + 1];
        int g = lane >> 3, j = lane & 7;
        if (FIN == 16) {
            __half2 acc = __floats2half2_rn(0.f, 0.f);
            for (int e = s0 + g; e < s1; e += 8) {
                int s = (int)src_sorted[e];
                acc = __hadd2(acc, ((const __half2*)(hin + (size_t)s * LDI))[j]);
            }
            #pragma unroll
            for (int m = 8; m < 64; m <<= 1) acc = __hadd2(acc, shfl_xor_h2(acc, m));
            if (g == 0) {
                float2 f = __half22float2(acc);
                gbuf[w][2 * j] = f.x; gbuf[w][2 * j + 1] = f.y;
            }
        } else {
            __half2 a0 = __floats2half2_rn(0.f, 0.f), a1 = a0, a2 = a0, a3 = a0;
            for (int e = s0 + g; e < s1; e += 8) {
                int s = (int)src_sorted[e];
                uint4 q = ((const uint4*)(hin + (size_t)s * LDI))[j];
                a0 = __hadd2(a0, *(__half2*)&q.x);
                a1 = __hadd2(a1, *(__half2*)&q.y);
                a2 = __hadd2(a2, *(__half2*)&q.z);
                a3 = __hadd2(a3, *(__half2*)&q.w);
            }
            #pragma unroll
            for (int m = 8; m < 64; m <<= 1) {
                a0 = __hadd2(a0, shfl_xor_h2(a0, m));
                a1 = __hadd2(a1, shfl_xor_h2(a1, m));
                a2 = __hadd2(a2, shfl_xor_h2(a2, m));
                a3 = __hadd2(a3, shfl_xor_h2(a3, m));
            }
            if (g == 0 && j < 6) {       // features 8j..8j+7 (j>=6 is padding)
                float2 f0 = __half22float2(a0), f1 = __half22float2(a1);
                float2 f2 = __half22float2(a2), f3 = __half22float2(a3);
                int f = 8 * j;
                gbuf[w][f + 0] = f0.x; gbuf[w][f + 1] = f0.y;
                gbuf[w][f + 2] = f1.x; gbuf[w][f + 3] = f1.y;
                gbuf[w][f + 4] = f2.x; gbuf[w][f + 5] = f2.y;
                gbuf[w][f + 6] = f3.x; gbuf[w][f + 7] = f3.y;
            }
        }
        if (lane < FIN) hbuf[w][lane] = __half2float(hin[(size_t)node * LDI + lane]);
    }
    __syncthreads();
    if (node < N) {
        int f = lane;
        if (f < 48) {
            float acc = b[f];
            #pragma unroll
            for (int k = 0; k < FIN; ++k)
                acc += hbuf[w][k] * Wr[k * 48 + f] + gbuf[w][k] * Wm[k * 48 + f];
            float4 ea = EA[node];
            acc += ea.x * Wm[(FIN + 0) * 48 + f] + ea.y * Wm[(FIN + 1) * 48 + f]
                 + ea.z * Wm[(FIN + 2) * 48 + f] + ea.w * Wm[(FIN + 3) * 48 + f];
            hout[(size_t)node * 64 + f] = __float2half(LRELU(acc));
        } else {
            hout[(size_t)node * 64 + f] = __float2half(0.f);   // pad
        }
    }
}

// ---------------- high-occupancy atomic readout (h rows padded to 64) ----------------
__global__ __launch_bounds__(256) void readout_atomic(const __half* __restrict__ h,
                                                      const int* __restrict__ batch,
                                                      const float* __restrict__ invcnt,
                                                      float* __restrict__ hcat,
                                                      int N, int c, int l) {
    int t = threadIdx.x;
    int lane = t & 63;
    int j = t & 7;
    int gid = (blockIdx.x * 256 + t) >> 3;   // global 8-lane group id
    int n0 = gid * c, n1 = min(n0 + c, N);
    float2 a0 = {0.f, 0.f}, a1 = {0.f, 0.f}, a2 = {0.f, 0.f};
    int cg = -1;
    for (int n = n0; n < n1; ++n) {
        int g = batch[n];
        if (g != cg) {
            if (cg >= 0) {
                float s = invcnt[cg];
                float* dst = hcat + cg * 144 + l * 48;
                atomicAdd(dst + 2 * j, a0.x * s);      atomicAdd(dst + 2 * j + 1, a0.y * s);
                atomicAdd(dst + 16 + 2 * j, a1.x * s); atomicAdd(dst + 17 + 2 * j, a1.y * s);
                atomicAdd(dst + 32 + 2 * j, a2.x * s); atomicAdd(dst + 33 + 2 * j, a2.y * s);
            }
            cg = g;
            a0 = make_float2(0.f, 0.f); a1 = a0; a2 = a0;
        }
        const __half2* hp = (const __half2*)(h + (size_t)n * 64);
        float2 v0 = __half22float2(hp[j]);
        float2 v1 = __half22float2(hp[8 + j]);
        float2 v2 = __half22float2(hp[16 + j]);
        a0.x += v0.x; a0.y += v0.y;
        a1.x += v1.x; a1.y += v1.y;
        a2.x += v2.x; a2.y += v2.y;
    }
    // wave-level combine when all 8 groups in this wave ended on the same graph
    int lead = __shfl(cg, 0);
    bool uni = __all(cg == lead) && lead >= 0;
    if (uni) {
        #pragma unroll
        for (int m = 8; m < 64; m <<= 1) {
            a0.x += __shfl_xor(a0.x, m); a0.y += __shfl_xor(a0.y, m);
            a1.x += __shfl_xor(a1.x, m); a1.y += __shfl_xor(a1.y, m);
            a2.x += __shfl_xor(a2.x, m); a2.y += __shfl_xor(a2.y, m);
        }
        if (lane < 8) {
            float s = invcnt[lead];
            float* dst = hcat + lead * 144 + l * 48;
            atomicAdd(dst + 2 * j, a0.x * s);      atomicAdd(dst + 2 * j + 1, a0.y * s);
            atomicAdd(dst + 16 + 2 * j, a1.x * s); atomicAdd(dst + 17 + 2 * j, a1.y * s);
            atomicAdd(dst + 32 + 2 * j, a2.x * s); atomicAdd(dst + 33 + 2 * j, a2.y * s);
        }
    } else if (cg >= 0) {
        float s = invcnt[cg];
        float* dst = hcat + cg * 144 + l * 48;
        atomicAdd(dst + 2 * j, a0.x * s);      atomicAdd(dst + 2 * j + 1, a0.y * s);
        atomicAdd(dst + 16 + 2 * j, a1.x * s); atomicAdd(dst + 17 + 2 * j, a1.y * s);
        atomicAdd(dst + 32 + 2 * j, a2.x * s); atomicAdd(dst + 33 + 2 * j, a2.y * s);
    }
}

// ---------------- final MLP: one block per graph (hcat already means) ----------------
__global__ __launch_bounds__(128) void mlp_kernel(const float* __restrict__ hcat,
                                                  const float* __restrict__ Wl1, const float* __restrict__ bl1,
                                                  const float* __restrict__ Wl2, const float* __restrict__ bl2,
                                                  const float* __restrict__ Wf, const float* __restrict__ bf,
                                                  float* __restrict__ out) {
    int g = blockIdx.x, t = threadIdx.x;
    __shared__ float buf[144];
    __shared__ float l1[128];
    for (int i = t; i < 144; i += 128) buf[i] = hcat[g * 144 + i];
    __syncthreads();
    float acc = bl1[t];
    for (int k = 0; k < 144; ++k) acc += buf[k] * Wl1[k * 128 + t];
    acc = LRELU(acc);
    l1[t] = acc;
    __syncthreads();
    float acc2 = bl2[t];
    for (int k = 0; k < 128; ++k) acc2 += l1[k] * Wl2[k * 128 + t];
    acc2 = LRELU(acc2);
    __syncthreads();
    buf[t] = acc2;
    __syncthreads();
    if (t < 4) {
        float a = bf[t];
        for (int k = 0; k < 128; ++k) a += buf[k] * Wf[k * 4 + t];
        out[g * 4 + t] = a;
    }
}

extern "C" void kernel_launch(void* const* d_in, const int* in_sizes, int n_in,
                              void* d_out, int out_size, void* d_ws, size_t ws_size,
                              hipStream_t stream) {
    const float* x     = (const float*)d_in[0];
    const float* eattr = (const float*)d_in[1];
    const float* Wr0 = (const float*)d_in[2];
    const float* Wm0 = (const float*)d_in[3];
    const float* b0  = (const float*)d_in[4];
    const float* Wr1 = (const float*)d_in[5];
    const float* Wm1 = (const float*)d_in[6];
    const float* b1  = (const float*)d_in[7];
    const float* Wr2 = (const float*)d_in[8];
    const float* Wm2 = (const float*)d_in[9];
    const float* b2  = (const float*)d_in[10];
    const float* Wl1 = (const float*)d_in[11];
    const float* bl1 = (const float*)d_in[12];
    const float* Wl2 = (const float*)d_in[13];
    const float* bl2 = (const float*)d_in[14];
    const float* Wf  = (const float*)d_in[15];
    const float* bf  = (const float*)d_in[16];
    const int* ei    = (const int*)d_in[17];
    const int* batch = (const int*)d_in[18];

    int N = in_sizes[0] / 16;
    int E = in_sizes[1] / 4;
    int NB = (N + BWN - 1) / BWN;
    int NBLK = (E + EPB - 1) / EPB;

    // ---- workspace layout (16B-aligned first) ----
    char* p = (char*)d_ws;
    float4* EA       = (float4*)p;                p += (size_t)N * 16;
    uint2* eab       = (uint2*)p;                 p += (size_t)E * 8;
    uint2* ea_sorted = (uint2*)p;                 p += (size_t)E * 8;
    __half* xn   = (__half*)p;                    p += (size_t)N * 16 * 2;
    __half* h16a = (__half*)p;                    p += (size_t)N * 64 * 2;   // padded rows
    __half* h16b = (__half*)p;                    p += (size_t)N * 64 * 2;
    uint* metab      = (uint*)p;                  p += (size_t)E * 4;
    uint* src_sorted = (uint*)p;                  p += (size_t)E * 4;
    uint* cnt        = (uint*)p;                  p += (size_t)NBLK * NB * 4;
    uint* total      = (uint*)p;                  p += (size_t)NB * 4;
    uint* base       = (uint*)p;                  p += (size_t)(NB + 1) * 4;
    int*  offs       = (int*)p;                   p += (size_t)(N + 1) * 4;
    float* estats    = (float*)p;                 p += 8 * 4;
    float* xstats    = (float*)p;                 p += 32 * 4;
    float* hcat      = (float*)p;                 p += 64 * 144 * 4;
    float* invcnt    = (float*)p;                 p += 64 * 4;

    // zero: estats + xstats + hcat + invcnt (contiguous)
    hipMemsetAsync(estats, 0, (8 + 32 + 64 * 144 + 64) * sizeof(float), stream);

    int n4 = N * 4;
    pass1<<<NXB + NEB + NBLK, 256, 0, stream>>>((const float4*)x, n4, (const float4*)eattr, E,
                                                ei + E, xstats, estats, cnt, NB);
    xnorm_kernel<<<256, 256, 0, stream>>>((const float4*)x, (__half2*)xn, xstats, n4, 1.f / N);
    scanB<<<NB, 256, 0, stream>>>(cnt, total, NBLK, NB);
    scanB2<<<1, 256, 0, stream>>>(total, base, NB, batch, N, invcnt);
    scatterC<<<NBLK, 256, 0, stream>>>(ei, (const float4*)eattr, cnt, base, estats,
                                       metab, eab, E, NB, 1.f / E);
    sort2<<<NB, 256, 0, stream>>>(metab, eab, base, src_sorted, ea_sorted, offs, EA, N, E);

    int c = (N + NRB * 32 - 1) / (NRB * 32);   // nodes per 8-lane group
    conv_kernel<16, 16><<<(N + 3) / 4, 256, 0, stream>>>(xn, EA, offs, src_sorted, Wr0, Wm0, b0, h16a, N);
    readout_atomic<<<NRB, 256, 0, stream>>>(h16a, batch, invcnt, hcat, N, c, 0);
    conv_kernel<48, 64><<<(N + 3) / 4, 256, 0, stream>>>(h16a, EA, offs, src_sorted, Wr1, Wm1, b1, h16b, N);
    readout_atomic<<<NRB, 256, 0, stream>>>(h16b, batch, invcnt, hcat, N, c, 1);
    conv_kernel<48, 64><<<(N + 3) / 4, 256, 0, stream>>>(h16b, EA, offs, src_sorted, Wr2, Wm2, b2, h16a, N);
    readout_atomic<<<NRB, 256, 0, stream>>>(h16a, batch, invcnt, hcat, N, c, 2);

    mlp_kernel<<<64, 128, 0, stream>>>(hcat, Wl1, bl1, Wl2, bl2, Wf, bf, (float*)d_out);
}